// Round 1
// baseline (103.481 us; speedup 1.0000x reference)
//
#include <hip/hip_runtime.h>

// y = relu(x @ W1 + b1) @ W2 + b2
// x: [B, 64] f32, W1: [64, 32] f32, b1: [32], W2: [32, 10] f32, b2: [10]
// One batch row per thread; weights are wave-uniform (scalar-cache) loads.

#define N_IN  64
#define N_MID 32
#define N_OUT 10

__global__ __launch_bounds__(256)
void livenet_fused_mlp(const float* __restrict__ x,
                       const float* __restrict__ W1,
                       const float* __restrict__ b1,
                       const float* __restrict__ W2,
                       const float* __restrict__ b2,
                       float* __restrict__ out,
                       int batch) {
    int row = blockIdx.x * blockDim.x + threadIdx.x;
    if (row >= batch) return;

    // Load this row's 64 inputs as 16 float4s (256 B, 16 B/lane per instr).
    float xr[N_IN];
    const float4* xp = reinterpret_cast<const float4*>(x + (size_t)row * N_IN);
    #pragma unroll
    for (int k = 0; k < N_IN / 4; ++k) {
        float4 v = xp[k];
        xr[4 * k + 0] = v.x;
        xr[4 * k + 1] = v.y;
        xr[4 * k + 2] = v.z;
        xr[4 * k + 3] = v.w;
    }

    // Layer 1: h = relu(x @ W1 + b1). W1 indexed with compile-time constants
    // -> uniform address -> s_load; b1 likewise.
    float h[N_MID];
    #pragma unroll
    for (int j = 0; j < N_MID; ++j) h[j] = b1[j];

    #pragma unroll
    for (int i = 0; i < N_IN; ++i) {
        float xi = xr[i];
        #pragma unroll
        for (int j = 0; j < N_MID; ++j) {
            h[j] = fmaf(xi, W1[i * N_MID + j], h[j]);
        }
    }
    #pragma unroll
    for (int j = 0; j < N_MID; ++j) h[j] = fmaxf(h[j], 0.0f);

    // Layer 2: y = h @ W2 + b2.
    float y[N_OUT];
    #pragma unroll
    for (int o = 0; o < N_OUT; ++o) y[o] = b2[o];

    #pragma unroll
    for (int j = 0; j < N_MID; ++j) {
        float hj = h[j];
        #pragma unroll
        for (int o = 0; o < N_OUT; ++o) {
            y[o] = fmaf(hj, W2[j * N_OUT + o], y[o]);
        }
    }

    // Store 10 floats = 5 x float2 (row*40 B is 8B-aligned; waves contiguous).
    float2* op = reinterpret_cast<float2*>(out + (size_t)row * N_OUT);
    #pragma unroll
    for (int o = 0; o < N_OUT / 2; ++o) {
        op[o] = make_float2(y[2 * o], y[2 * o + 1]);
    }
}

extern "C" void kernel_launch(void* const* d_in, const int* in_sizes, int n_in,
                              void* d_out, int out_size, void* d_ws, size_t ws_size,
                              hipStream_t stream) {
    const float* x  = (const float*)d_in[0];
    const float* W1 = (const float*)d_in[1];
    const float* b1 = (const float*)d_in[2];
    const float* W2 = (const float*)d_in[3];
    const float* b2 = (const float*)d_in[4];
    float* out = (float*)d_out;

    int batch = in_sizes[0] / N_IN;   // 1048576
    int block = 256;
    int grid = (batch + block - 1) / block;
    livenet_fused_mlp<<<grid, block, 0, stream>>>(x, W1, b1, W2, b2, out, batch);
}

// Round 2
// 63.667 us; speedup vs baseline: 1.6254x; 1.6254x over previous
//
#include <hip/hip_runtime.h>

// y = relu(x @ W1 + b1) @ W2 + b2  via bf16 MFMA (fp32 accumulate).
// x: [B, 64] f32, W1: [64, 32], b1: [32], W2: [32, 10], b2: [10], y: [B, 10] f32.
//
// Per wave-tile (16 batch rows):
//   A-frag (x):  lane l holds row (l&15), k = 8*(l>>4)+i  (i=0..7), two K-halves.
//   B-frag (W):  lane l holds col (l&15), k = 8*(l>>4)+i. Built once per wave.
//   C/D layout:  col = lane&15, row = (lane>>4)*4 + reg   (verified mapping).
// Layer-2 needs h transposed from C-layout to A-layout -> tiny per-wave LDS
// bounce (16 rows x 32 bf16, 80B row stride so b128 reads stay 16B-aligned
// and banks spread). Per-wave private LDS: no __syncthreads needed; same-wave
// DS ops complete in order; asm "memory" clobber pins compiler ordering.

#define N_IN  64
#define N_MID 32
#define N_OUT 10

#define WAVES_PER_BLOCK 4
#define TILES_PER_WAVE  4
#define ROWS_PER_TILE   16
#define ROWS_PER_BLOCK  (WAVES_PER_BLOCK * TILES_PER_WAVE * ROWS_PER_TILE)  // 256
#define H_STRIDE        80  // bytes per h-row in LDS (64 data + 16 pad, 16B-aligned)

typedef short bf16x8 __attribute__((ext_vector_type(8)));
typedef float f32x4  __attribute__((ext_vector_type(4)));

static __device__ __forceinline__ short f2bf(float f) {
    __bf16 h = (__bf16)f;             // HW RNE convert (v_cvt_pk_bf16_f32)
    return __builtin_bit_cast(short, h);
}

__global__ __launch_bounds__(256)
void livenet_mfma(const float* __restrict__ x,
                  const float* __restrict__ W1,
                  const float* __restrict__ b1,
                  const float* __restrict__ W2,
                  const float* __restrict__ b2,
                  float* __restrict__ out,
                  int batch) {
    __shared__ unsigned char h_lds_all[WAVES_PER_BLOCK][ROWS_PER_TILE * H_STRIDE];

    const int lane = threadIdx.x & 63;
    const int wave = threadIdx.x >> 6;
    const int g    = lane >> 4;   // 0..3 : k-group
    const int c    = lane & 15;   // 0..15: row (A) / col (B,C)

    unsigned char* h_lds = h_lds_all[wave];

    // ---- weight fragments, once per wave (W1: 8KB, L2-resident broadcast) ----
    bf16x8 w1f[2][2];  // [n-tile][k-half]
    #pragma unroll
    for (int n = 0; n < 2; ++n)
        #pragma unroll
        for (int p = 0; p < 2; ++p)
            #pragma unroll
            for (int i = 0; i < 8; ++i) {
                int k = p * 32 + 8 * g + i;
                w1f[n][p][i] = f2bf(W1[k * N_MID + n * 16 + c]);
            }

    bf16x8 w2f;
    #pragma unroll
    for (int i = 0; i < 8; ++i) {
        int k = 8 * g + i;
        w2f[i] = (c < N_OUT) ? f2bf(W2[k * N_OUT + c]) : (short)0;
    }

    const float b1v0 = b1[c];
    const float b1v1 = b1[16 + c];
    const float b2v  = (c < N_OUT) ? b2[c] : 0.0f;

    const size_t wave_row0 = (size_t)blockIdx.x * ROWS_PER_BLOCK
                           + (size_t)wave * (TILES_PER_WAVE * ROWS_PER_TILE);

    for (int t = 0; t < TILES_PER_WAVE; ++t) {
        const size_t rb = wave_row0 + (size_t)t * ROWS_PER_TILE;
        if (rb + ROWS_PER_TILE > (size_t)batch) break;

        // ---- load x in A-fragment order: row rb+c, k = 8g + {0..7}, +32 ----
        const float* xp = x + (rb + (size_t)c) * N_IN + 8 * g;
        const float4 v0 = *(const float4*)(xp + 0);
        const float4 v1 = *(const float4*)(xp + 4);
        const float4 v2 = *(const float4*)(xp + 32);
        const float4 v3 = *(const float4*)(xp + 36);

        bf16x8 a0, a1;
        a0[0] = f2bf(v0.x); a0[1] = f2bf(v0.y); a0[2] = f2bf(v0.z); a0[3] = f2bf(v0.w);
        a0[4] = f2bf(v1.x); a0[5] = f2bf(v1.y); a0[6] = f2bf(v1.z); a0[7] = f2bf(v1.w);
        a1[0] = f2bf(v2.x); a1[1] = f2bf(v2.y); a1[2] = f2bf(v2.z); a1[3] = f2bf(v2.w);
        a1[4] = f2bf(v3.x); a1[5] = f2bf(v3.y); a1[6] = f2bf(v3.z); a1[7] = f2bf(v3.w);

        // ---- layer 1: h = relu(x@W1 + b1), bias pre-loaded into acc ----
        f32x4 acc0 = {b1v0, b1v0, b1v0, b1v0};
        f32x4 acc1 = {b1v1, b1v1, b1v1, b1v1};
        acc0 = __builtin_amdgcn_mfma_f32_16x16x32_bf16(a0, w1f[0][0], acc0, 0, 0, 0);
        acc0 = __builtin_amdgcn_mfma_f32_16x16x32_bf16(a1, w1f[0][1], acc0, 0, 0, 0);
        acc1 = __builtin_amdgcn_mfma_f32_16x16x32_bf16(a0, w1f[1][0], acc1, 0, 0, 0);
        acc1 = __builtin_amdgcn_mfma_f32_16x16x32_bf16(a1, w1f[1][1], acc1, 0, 0, 0);

        // ---- relu + pack, transpose via per-wave LDS ----
        #pragma unroll
        for (int r = 0; r < 4; ++r) {
            const int rowr = 4 * g + r;  // C-layout row
            *(short*)(h_lds + rowr * H_STRIDE +      2 * c) = f2bf(fmaxf(acc0[r], 0.0f));
            *(short*)(h_lds + rowr * H_STRIDE + 32 + 2 * c) = f2bf(fmaxf(acc1[r], 0.0f));
        }
        __asm__ volatile("" ::: "memory");  // keep write->read order at compile level

        // ---- layer 2: A-frag of h: row = c, k = 8g+i -> 16B aligned b128 ----
        const bf16x8 hfrag = *(const bf16x8*)(h_lds + c * H_STRIDE + 16 * g);
        f32x4 acc2 = {b2v, b2v, b2v, b2v};
        acc2 = __builtin_amdgcn_mfma_f32_16x16x32_bf16(hfrag, w2f, acc2, 0, 0, 0);

        __asm__ volatile("" ::: "memory");  // keep read before next tile's writes

        // ---- store: y[rb + 4g + r][c], c < 10 ----
        if (c < N_OUT) {
            #pragma unroll
            for (int r = 0; r < 4; ++r) {
                out[(rb + 4 * g + r) * N_OUT + c] = acc2[r];
            }
        }
    }
}

extern "C" void kernel_launch(void* const* d_in, const int* in_sizes, int n_in,
                              void* d_out, int out_size, void* d_ws, size_t ws_size,
                              hipStream_t stream) {
    const float* x  = (const float*)d_in[0];
    const float* W1 = (const float*)d_in[1];
    const float* b1 = (const float*)d_in[2];
    const float* W2 = (const float*)d_in[3];
    const float* b2 = (const float*)d_in[4];
    float* out = (float*)d_out;

    int batch = in_sizes[0] / N_IN;                       // 1048576
    int grid  = (batch + ROWS_PER_BLOCK - 1) / ROWS_PER_BLOCK;  // 4096
    livenet_mfma<<<grid, 256, 0, stream>>>(x, W1, b1, W2, b2, out, batch);
}